// Round 1
// baseline (547.726 us; speedup 1.0000x reference)
//
#include <hip/hip_runtime.h>

#define NB 256       // batch
#define NT_ 2048     // timesteps
#define DIN 64
#define DH 128
#define HB 64        // h-channels per block (h-split: 2 blocks per batch)
#define TT 32        // time tile
#define NTILES (NT_ / TT)   // 64

// LDS: only the ff handoff buffers now: 2*32*64*4 = 16 KB/block.
// x is read via s_load_dwordx16 straight into SGPRs (wave-uniform rows),
// W is register-resident (64 VGPRs) under the 102-VGPR cap from
// __launch_bounds__(576, 5)  -> 18 waves/CU (2 blocks) still fits.

typedef __attribute__((ext_vector_type(16))) float f32x16;

__device__ __forceinline__ void scan_tile(const float* ffs_buf, float& mem, float& spk,
                                          float* op, int t0, int lane) {
    #pragma unroll
    for (int tt = 0; tt < TT; ++tt) {
        float f = ffs_buf[tt * HB + lane];
        mem = fmaf(0.9f, mem, f - spk);
        // sigmoid(5*(mem-1)) = 1/(1+2^(-5*log2e*(mem-1)))
        float e = __builtin_amdgcn_exp2f(-7.213475204444817f * (mem - 1.f));
        spk = __builtin_amdgcn_rcpf(1.f + e);
        op[(size_t)(t0 + tt) * DH] = spk;
    }
}

// 16 fp32 of x (SGPR, broadcast at operand read) * 16 k-slice of W (VGPR)
#define QUART(XA, KB) { \
    float4 w; \
    w = w4[(KB)+0]; s0=fmaf(XA[0] ,w.x,s0); s1=fmaf(XA[1] ,w.y,s1); s2=fmaf(XA[2] ,w.z,s2); s3=fmaf(XA[3] ,w.w,s3); \
    w = w4[(KB)+1]; s0=fmaf(XA[4] ,w.x,s0); s1=fmaf(XA[5] ,w.y,s1); s2=fmaf(XA[6] ,w.z,s2); s3=fmaf(XA[7] ,w.w,s3); \
    w = w4[(KB)+2]; s0=fmaf(XA[8] ,w.x,s0); s1=fmaf(XA[9] ,w.y,s1); s2=fmaf(XA[10],w.z,s2); s3=fmaf(XA[11],w.w,s3); \
    w = w4[(KB)+3]; s0=fmaf(XA[12],w.x,s0); s1=fmaf(XA[13],w.y,s1); s2=fmaf(XA[14],w.z,s2); s3=fmaf(XA[15],w.w,s3); \
}

__global__ __launch_bounds__(576, 5) void snn_fused_kernel(
    const float* __restrict__ x, const float* __restrict__ W,
    const float* __restrict__ bias, float* __restrict__ out)
{
    __shared__ float ffs[2][TT * HB];   // produced ff tiles (double-buffered)

    const int tid   = threadIdx.x;
    const int wv    = tid >> 6;         // 0..8 (waves 0-7: GEMM, wave 8: scan)
    const int lane  = tid & 63;
    const int b     = blockIdx.x >> 1;
    const int hhalf = blockIdx.x & 1;

    const float* xb = x + (size_t)b * NT_ * DIN;

    if (wv < 8) {
        // ---------------- producer: GEMM waves ----------------
        // each thread: one h (= hhalf*64 + lane), 4 wave-uniform timesteps/tile
        const int h = hhalf * HB + lane;
        float4 w4[16];
        const float4* Wrow = (const float4*)(W + h * DIN);
        #pragma unroll
        for (int kk = 0; kk < 16; ++kk) w4[kk] = Wrow[kk];
        const float bh = bias[h];

        // wave-uniform local row base (readfirstlane -> provably uniform)
        const int t0 = __builtin_amdgcn_readfirstlane(wv) * 4;

        __syncthreads();   // [barrier 0]

        for (int it = 0; it < NTILES; ++it) {
            const int buf = it & 1;
            #pragma unroll
            for (int i = 0; i < 4; ++i) {
                const float* xrow = xb + (size_t)(it * TT + t0 + i) * DIN;
                f32x16 xa0, xa1, xa2, xa3;
                // 4x s_load_dwordx16: full 64-float x row into SGPRs.
                // lgkmcnt(0) inside the SAME asm -> consumers are dataflow-safe.
                asm volatile(
                    "s_load_dwordx16 %0, %4, 0x0\n\t"
                    "s_load_dwordx16 %1, %4, 0x40\n\t"
                    "s_load_dwordx16 %2, %4, 0x80\n\t"
                    "s_load_dwordx16 %3, %4, 0xc0\n\t"
                    "s_waitcnt lgkmcnt(0)"
                    : "=&s"(xa0), "=&s"(xa1), "=&s"(xa2), "=&s"(xa3)
                    : "s"(xrow));

                float s0 = 0.f, s1 = 0.f, s2 = 0.f, s3 = 0.f;
                QUART(xa0, 0)
                QUART(xa1, 4)
                QUART(xa2, 8)
                QUART(xa3, 12)
                ffs[buf][(t0 + i) * HB + lane] = (s0 + s1) + (s2 + s3) + bh;
            }
            __syncthreads();   // [barrier 1+it] ff tile it published
        }
    } else {
        // ---------------- consumer: scan wave ----------------
        float mem = 0.f, spk = 0.f;
        float* op = out + (size_t)b * NT_ * DH + hhalf * HB + lane;

        __syncthreads();   // [barrier 0]
        for (int it = 0; it < NTILES; ++it) {
            if (it > 0) {
                scan_tile(ffs[(it - 1) & 1], mem, spk, op, (it - 1) * TT, lane);
            }
            __syncthreads();   // [barrier 1+it]
        }
        // drain: last tile (GEMM waves have exited; no barrier needed)
        scan_tile(ffs[(NTILES - 1) & 1], mem, spk, op, (NTILES - 1) * TT, lane);
    }
}

extern "C" void kernel_launch(void* const* d_in, const int* in_sizes, int n_in,
                              void* d_out, int out_size, void* d_ws, size_t ws_size,
                              hipStream_t stream) {
    const float* x  = (const float*)d_in[0];
    const float* W  = (const float*)d_in[1];
    const float* bb = (const float*)d_in[2];
    float* out = (float*)d_out;
    snn_fused_kernel<<<dim3(NB * 2), dim3(576), 0, stream>>>(x, W, bb, out);
}